// Round 10
// baseline (88.311 us; speedup 1.0000x reference)
//
#include <hip/hip_runtime.h>
#include <cstdint>

#define F_IN   8
#define HID    64
#define F_OUTD 8
#define RDIM   256
#define CDIM   4096
#define NSETS  3
#define NIND   4096
#define MDIM   4096
#define MAXL   64
#define GC     16
#define MPW    4

using short8 = __attribute__((ext_vector_type(8))) short;
using f32x4  = __attribute__((ext_vector_type(4))) float;

// hardware packed f32->bf16 (RNE), low word = a
__device__ inline unsigned int cvtpk(float a, float b) {
    unsigned int r;
    asm("v_cvt_pk_bf16_f32 %0, %1, %2" : "=v"(r) : "v"(a), "v"(b));
    return r;
}
// packed unsigned 16-bit max (== bf16 max for nonnegative values)
__device__ inline unsigned int pkmaxu(unsigned int a, unsigned int b) {
    unsigned int r;
    asm("v_pk_max_u16 %0, %1, %2" : "=v"(r) : "v"(a), "v"(b));
    return r;
}

// ---------------- input prep: in [F][R][C] f32 -> inT2 [C][R][F] bf16 ----------
__global__ __launch_bounds__(256)
void prep_in(const float* __restrict__ in, unsigned short* __restrict__ out) {
    const int PADH = 264;                       // halfs per c-row (528B)
    __shared__ unsigned short tile[32 * PADH];
    int c0 = blockIdx.x * 32, r0 = blockIdx.y * 32;
    int t = threadIdx.x;
    int tx = t & 31, ty = t >> 5;
#pragma unroll
    for (int f = 0; f < 8; f += 2)
#pragma unroll
        for (int rr = 0; rr < 4; rr++) {
            int r = ty + rr * 8;
            float v0 = in[((size_t)f * RDIM + (r0 + r)) * CDIM + c0 + tx];
            float v1 = in[((size_t)(f + 1) * RDIM + (r0 + r)) * CDIM + c0 + tx];
            *(unsigned int*)&tile[tx * PADH + r * 8 + f] = cvtpk(v0, v1);
        }
    __syncthreads();
    int r = t & 31, cl = t >> 5;
#pragma unroll
    for (int cc = 0; cc < 4; cc++) {
        int c = cc * 8 + cl;
        uint4 v = *(const uint4*)&tile[c * PADH + r * 8];
        *(uint4*)(out + (((size_t)(c0 + c) * RDIM) + (r0 + r)) * 8) = v;
    }
}

// ---------------- setup: inverse perms + mergecnt zero + weight prep ----------
// inv[si][c0]=k s.t. ind_i[s][k][0]==c0; block (0,0) converts weights to bf16.
// w2's columns are permuted by tau so that layer-1's packed relu output
// (D-fragment order) is directly the layer-2 B-fragment:
//   tau(32*hi + 8*q + e) = 32*hi + 16*(e>>2) + 4*q + (e&3)
__global__ void build_inv(const int* __restrict__ ind0, const int* __restrict__ ind1,
                          const int* __restrict__ ind2,
                          const float* __restrict__ w1, const float* __restrict__ w2,
                          int* __restrict__ inv, int* __restrict__ mergecnt,
                          unsigned short* __restrict__ w1bf, unsigned short* __restrict__ w2bf) {
    int k  = blockIdx.x * 256 + threadIdx.x;
    int si = blockIdx.y;
    int s_ = si / 3, i_ = si % 3;
    const int* ind = (i_ == 0 ? ind0 : (i_ == 1 ? ind1 : ind2)) + (size_t)s_ * NIND * 2;
    int c0 = ind[2 * k];
    inv[(size_t)si * NIND + c0] = k;
    if (si == 0) mergecnt[k] = 0;
    if (blockIdx.x == 0 && blockIdx.y == 0) {
        int t = threadIdx.x;
        for (int i = t; i < 64 * 32; i += 256) {
            int j = i >> 5, kk = i & 31;
            w1bf[i] = (kk < 24) ? (unsigned short)(cvtpk(w1[j * 24 + kk], 0.f) & 0xffff) : 0;
        }
        for (int i = t; i < 16 * 64; i += 256) {
            int f = i >> 6, kg = i & 63;
            int hi = kg >> 5, q = (kg >> 3) & 3, e = kg & 7;
            int j = (hi << 5) + ((e >> 2) << 4) + (q << 2) + (e & 3);   // tau
            w2bf[i] = (f < 8) ? (unsigned short)(cvtpk(w2[f * 64 + j], 0.f) & 0xffff) : 0;
        }
    }
}

// ---------------- bucket-invert the scatter into ONE merged list per column --
// mergelist[c][slot] = s*MDIM + m  (the d-tile index contributing to column c)
__global__ void build_buckets(const int* __restrict__ ind0, const int* __restrict__ ind1,
                              const int* __restrict__ ind2, const int* __restrict__ mix,
                              int* __restrict__ mergecnt, int* __restrict__ mergelist) {
    int m  = blockIdx.x * 256 + threadIdx.x;
    int si = blockIdx.y;
    int s_ = si / 3, i_ = si % 3;
    const int* ind = (i_ == 0 ? ind0 : (i_ == 1 ? ind1 : ind2)) + (size_t)s_ * NIND * 2;
    int mi = mix[(size_t)si * MDIM + m];
    int c  = ind[2 * mi + 1];
    int slot = atomicAdd(&mergecnt[c], 1);
    if (slot < MAXL) mergelist[(size_t)c * MAXL + slot] = s_ * MDIM + m;
}

// ---------------- MFMA MLP -> dense d[s*M+m][r][f] bf16 (clamped at 0) -----
// One wave per (s, half-of-r, group of MPW m). Fully in-register; w2 columns
// pre-permuted by tau so layer-1's packed relu output IS the layer-2 B frag.
// R8-verbatim body (fmaxf-then-cvtpk: fmaxf also squashes any NaN; 2-deep
// prefetch; q==3 keeps a zero register fragment).
__global__ __launch_bounds__(256, 2)
void mlp_store(const unsigned short* __restrict__ inT2,
               const unsigned short* __restrict__ w1bf,
               const unsigned short* __restrict__ w2bf,
               const float* __restrict__ b1, const float* __restrict__ b2,
               const int* __restrict__ ind0, const int* __restrict__ ind1,
               const int* __restrict__ ind2, const int* __restrict__ mix,
               const int* __restrict__ inv,
               unsigned short* __restrict__ dbuf) {
    int t    = threadIdx.x;
    int wave = t >> 6, lane = t & 63;
    int lo = lane & 15, q = lane >> 4;

    int wid  = blockIdx.x * 4 + wave;    // 0..6143
    int mgrp = wid & 1023;
    int half = (wid >> 10) & 1;
    int s_   = wid >> 11;
    int m0   = mgrp * MPW;

    short8 A1[4], A2[2];
#pragma unroll
    for (int tt = 0; tt < 4; tt++)
        A1[tt] = *(const short8*)(w1bf + ((16 * tt + lo) << 5) + (q << 3));
#pragma unroll
    for (int kk = 0; kk < 2; kk++)
        A2[kk] = *(const short8*)(w2bf + (lo << 6) + (kk << 5) + (q << 3));

    // biases as MFMA C-operand fragments
    f32x4 bbv[4];
#pragma unroll
    for (int tt = 0; tt < 4; tt++)
#pragma unroll
        for (int rg = 0; rg < 4; rg++)
            bbv[tt][rg] = b1[16 * tt + 4 * q + rg];
    f32x4 b2f;
#pragma unroll
    for (int rg = 0; rg < 4; rg++) {
        int f = 4 * q + rg;
        b2f[rg] = (f < 8) ? b2[f] : 0.f;
    }

    // batched index chase: 3 rounds of MPW independent loads
    int gq[MPW] = {0, 0, 0, 0};
    if (q < 3) {
        int si = s_ * 3 + q;
        const int* indq = (q == 0 ? ind0 : (q == 1 ? ind1 : ind2)) + (size_t)s_ * NIND * 2;
        int mi[MPW], kk[MPW];
#pragma unroll
        for (int u = 0; u < MPW; u++) mi[u] = mix[(size_t)si * MDIM + m0 + u];
#pragma unroll
        for (int u = 0; u < MPW; u++) kk[u] = inv[(size_t)si * NIND + mi[u]];
#pragma unroll
        for (int u = 0; u < MPW; u++) gq[u] = indq[2 * kk[u] + 1];
    }
    const unsigned short* srcs[MPW];
#pragma unroll
    for (int u = 0; u < MPW; u++)
        srcs[u] = inT2 + ((size_t)gq[u] * RDIM + half * 128 + lo) * 8;

    unsigned short* dst = dbuf + (size_t)(s_ * MDIM + m0) * 2048 + half * 1024 + lo * 8 + q * 4;

    union U { unsigned int u[4]; short8 s; };
    const short8 zero8 = {0, 0, 0, 0, 0, 0, 0, 0};

    short8 Bcur = zero8;
    if (q < 3) Bcur = *(const short8*)srcs[0];
#pragma unroll
    for (int it = 0; it < MPW * 8; it++) {
        const int u = it >> 3, j = it & 7;
        short8 Bnext = Bcur;
        if (it < MPW * 8 - 1 && q < 3)
            Bnext = *(const short8*)(srcs[(it + 1) >> 3] + ((it + 1) & 7) * 128);

        f32x4 a0 = __builtin_amdgcn_mfma_f32_16x16x32_bf16(A1[0], Bcur, bbv[0], 0, 0, 0);
        f32x4 a1 = __builtin_amdgcn_mfma_f32_16x16x32_bf16(A1[1], Bcur, bbv[1], 0, 0, 0);
        f32x4 a2 = __builtin_amdgcn_mfma_f32_16x16x32_bf16(A1[2], Bcur, bbv[2], 0, 0, 0);
        f32x4 a3 = __builtin_amdgcn_mfma_f32_16x16x32_bf16(A1[3], Bcur, bbv[3], 0, 0, 0);

        // relu (fmaxf: also NaN-squashing) + bf16 pack: result IS the layer-2
        // B fragment (tau-permuted w2)
        U ba, bb;
        ba.u[0] = cvtpk(fmaxf(a0[0], 0.f), fmaxf(a0[1], 0.f));
        ba.u[1] = cvtpk(fmaxf(a0[2], 0.f), fmaxf(a0[3], 0.f));
        ba.u[2] = cvtpk(fmaxf(a1[0], 0.f), fmaxf(a1[1], 0.f));
        ba.u[3] = cvtpk(fmaxf(a1[2], 0.f), fmaxf(a1[3], 0.f));
        bb.u[0] = cvtpk(fmaxf(a2[0], 0.f), fmaxf(a2[1], 0.f));
        bb.u[1] = cvtpk(fmaxf(a2[2], 0.f), fmaxf(a2[3], 0.f));
        bb.u[2] = cvtpk(fmaxf(a3[0], 0.f), fmaxf(a3[1], 0.f));
        bb.u[3] = cvtpk(fmaxf(a3[2], 0.f), fmaxf(a3[3], 0.f));

        f32x4 o = __builtin_amdgcn_mfma_f32_16x16x32_bf16(A2[0], ba.s, b2f, 0, 0, 0);
        o = __builtin_amdgcn_mfma_f32_16x16x32_bf16(A2[1], bb.s, o, 0, 0, 0);

        if (q < 2) {   // store d (clamped at 0; negatives never beat zeros baseline)
            uint2 ov;
            ov.x = cvtpk(fmaxf(o[0], 0.f), fmaxf(o[1], 0.f));
            ov.y = cvtpk(fmaxf(o[2], 0.f), fmaxf(o[3], 0.f));
            *(uint2*)(dst + (size_t)u * 2048 + j * 128) = ov;
        }
        Bcur = Bnext;
    }
}

// ---------------- gather-max per dest column -> d_out [f][r][c] directly ------
// grid (CDIM/GC, 4); 1024-thread block = 16 waves; wave w owns column c0+w,
// lane = row within the 64-row slab. List length is wave-uniform -> zero
// divergence; each entry is one coalesced 1KB wave read. Hardened: full mlist
// init, clamped n/idx, NaN-squashing unpack (output is provably >= 0).
__global__ __launch_bounds__(1024)
void gather_max_t(const unsigned short* __restrict__ dbuf, const int* __restrict__ mergecnt,
                  const int* __restrict__ mergelist, float* __restrict__ out) {
    __shared__ unsigned int ldsP[4][64][20];   // [f/2][rloc][c] packed bf16 pairs
    __shared__ int mlist[GC][MAXL];
    int t = threadIdx.x;
    int w = t >> 6, lane = t & 63;
    int c0 = blockIdx.x * GC;
    int c  = c0 + w;

    mlist[w][lane] = 0;                           // full init (defensive)
    int n = mergecnt[c];
    n = n < 0 ? 0 : (n > MAXL ? MAXL : n);        // uniform across the wave
    if (lane < n) {
        int idx = mergelist[(size_t)c * MAXL + lane];
        idx = idx < 0 ? 0 : (idx >= NSETS * MDIM ? NSETS * MDIM - 1 : idx);
        mlist[w][lane] = idx;
    }
    __syncthreads();

    int r = blockIdx.y * 64 + lane;
    uint4 acc = make_uint4(0u, 0u, 0u, 0u);
    if (n > 0) {
        uint4 p = *(const uint4*)(dbuf + ((size_t)mlist[w][0] * RDIM + r) * 8);
        for (int e = 1; e < n; e++) {
            uint4 nx = *(const uint4*)(dbuf + ((size_t)mlist[w][e] * RDIM + r) * 8);
            acc.x = pkmaxu(acc.x, p.x); acc.y = pkmaxu(acc.y, p.y);
            acc.z = pkmaxu(acc.z, p.z); acc.w = pkmaxu(acc.w, p.w);
            p = nx;
        }
        acc.x = pkmaxu(acc.x, p.x); acc.y = pkmaxu(acc.y, p.y);
        acc.z = pkmaxu(acc.z, p.z); acc.w = pkmaxu(acc.w, p.w);
    }

    ldsP[0][lane][w] = acc.x;
    ldsP[1][lane][w] = acc.y;
    ldsP[2][lane][w] = acc.z;
    ldsP[3][lane][w] = acc.w;
    __syncthreads();

    // one (f-pair, row, c-quad) per thread: 1024 = 4 * 64 * 4.
    // fmaxf(x, 0) is identity on all legit values (>=0) and squashes NaN/neg.
    int f2 = t >> 8, rl = (t >> 2) & 63, cq = t & 3;
    uint4 v = *(const uint4*)&ldsP[f2][rl][cq * 4];
    float4 lo, hi;
    lo.x = fmaxf(__uint_as_float(v.x << 16), 0.f);
    hi.x = fmaxf(__uint_as_float(v.x & 0xffff0000u), 0.f);
    lo.y = fmaxf(__uint_as_float(v.y << 16), 0.f);
    hi.y = fmaxf(__uint_as_float(v.y & 0xffff0000u), 0.f);
    lo.z = fmaxf(__uint_as_float(v.z << 16), 0.f);
    hi.z = fmaxf(__uint_as_float(v.z & 0xffff0000u), 0.f);
    lo.w = fmaxf(__uint_as_float(v.w << 16), 0.f);
    hi.w = fmaxf(__uint_as_float(v.w & 0xffff0000u), 0.f);
    size_t rowoff = (size_t)blockIdx.y * 64 + rl;
    *(float4*)&out[((size_t)(2 * f2) * RDIM + rowoff) * CDIM + c0 + cq * 4] = lo;
    *(float4*)&out[((size_t)(2 * f2 + 1) * RDIM + rowoff) * CDIM + c0 + cq * 4] = hi;
}

extern "C" void kernel_launch(void* const* d_in, const int* in_sizes, int n_in,
                              void* d_out, int out_size, void* d_ws, size_t ws_size,
                              hipStream_t stream) {
    const float* input = (const float*)d_in[0];
    const float* w1    = (const float*)d_in[1];
    const float* b1    = (const float*)d_in[2];
    const float* w2    = (const float*)d_in[3];
    const float* b2    = (const float*)d_in[4];
    const int*   ind0  = (const int*)d_in[5];
    const int*   ind1  = (const int*)d_in[6];
    const int*   ind2  = (const int*)d_in[7];
    const int*   mix   = (const int*)d_in[8];

    const size_t MiB = 1ull << 20;
    char* ws = (char*)d_ws;
    unsigned short* inT2 = (unsigned short*)ws;                    // 16 MiB
    unsigned short* dbuf = (unsigned short*)(ws + 16 * MiB);       // 48 MiB
    char* tail = ws + 64 * MiB;
    int* inv       = (int*)tail;                                   // 144 KiB
    int* mergecnt  = (int*)(tail + 147456);                        // 16 KiB
    int* mergelist = (int*)(tail + 147456 + 16384);                // 1 MiB
    unsigned short* w1bf = (unsigned short*)(tail + 147456 + 16384 + (size_t)CDIM * MAXL * 4);
    unsigned short* w2bf = w1bf + 64 * 32;

    prep_in<<<dim3(CDIM / 32, RDIM / 32), 256, 0, stream>>>(input, inT2);
    build_inv<<<dim3(NIND / 256, 9), 256, 0, stream>>>(ind0, ind1, ind2, w1, w2,
                                                       inv, mergecnt, w1bf, w2bf);
    build_buckets<<<dim3(MDIM / 256, 9), 256, 0, stream>>>(ind0, ind1, ind2, mix,
                                                           mergecnt, mergelist);
    mlp_store<<<NSETS * 2 * (MDIM / MPW) / 4, 256, 0, stream>>>(inT2, w1bf, w2bf, b1, b2,
                                                                ind0, ind1, ind2, mix, inv, dbuf);
    gather_max_t<<<dim3(CDIM / GC, 4), 1024, 0, stream>>>(dbuf, mergecnt, mergelist,
                                                          (float*)d_out);
}

// Round 11
// 86.990 us; speedup vs baseline: 1.0152x; 1.0152x over previous
//
#include <hip/hip_runtime.h>
#include <cstdint>

#define F_IN   8
#define HID    64
#define F_OUTD 8
#define RDIM   256
#define CDIM   4096
#define NSETS  3
#define NIND   4096
#define MDIM   4096
#define MAXL   64
#define GC     16
#define MPW    4

using short8 = __attribute__((ext_vector_type(8))) short;
using f32x4  = __attribute__((ext_vector_type(4))) float;

// hardware packed f32->bf16 (RNE), low word = a
__device__ inline unsigned int cvtpk(float a, float b) {
    unsigned int r;
    asm("v_cvt_pk_bf16_f32 %0, %1, %2" : "=v"(r) : "v"(a), "v"(b));
    return r;
}
// packed unsigned 16-bit max (== bf16 max for nonnegative values)
__device__ inline unsigned int pkmaxu(unsigned int a, unsigned int b) {
    unsigned int r;
    asm("v_pk_max_u16 %0, %1, %2" : "=v"(r) : "v"(a), "v"(b));
    return r;
}

// ---------------- input prep: in [F][R][C] f32 -> inT2 [C][R][F] bf16 ----------
__global__ __launch_bounds__(256)
void prep_in(const float* __restrict__ in, unsigned short* __restrict__ out) {
    const int PADH = 264;                       // halfs per c-row (528B)
    __shared__ unsigned short tile[32 * PADH];
    int c0 = blockIdx.x * 32, r0 = blockIdx.y * 32;
    int t = threadIdx.x;
    int tx = t & 31, ty = t >> 5;
#pragma unroll
    for (int f = 0; f < 8; f += 2)
#pragma unroll
        for (int rr = 0; rr < 4; rr++) {
            int r = ty + rr * 8;
            float v0 = in[((size_t)f * RDIM + (r0 + r)) * CDIM + c0 + tx];
            float v1 = in[((size_t)(f + 1) * RDIM + (r0 + r)) * CDIM + c0 + tx];
            *(unsigned int*)&tile[tx * PADH + r * 8 + f] = cvtpk(v0, v1);
        }
    __syncthreads();
    int r = t & 31, cl = t >> 5;
#pragma unroll
    for (int cc = 0; cc < 4; cc++) {
        int c = cc * 8 + cl;
        uint4 v = *(const uint4*)&tile[c * PADH + r * 8];
        *(uint4*)(out + (((size_t)(c0 + c) * RDIM) + (r0 + r)) * 8) = v;
    }
}

// ---------------- setup: inverse perms + mergecnt zero + weight prep ----------
// inv[si][c0]=k s.t. ind_i[s][k][0]==c0; block (0,0) converts weights to bf16.
// w2's columns are permuted by tau so that layer-1's packed relu output
// (D-fragment order) is directly the layer-2 B-fragment:
//   tau(32*hi + 8*q + e) = 32*hi + 16*(e>>2) + 4*q + (e&3)
__global__ void build_inv(const int* __restrict__ ind0, const int* __restrict__ ind1,
                          const int* __restrict__ ind2,
                          const float* __restrict__ w1, const float* __restrict__ w2,
                          int* __restrict__ inv, int* __restrict__ mergecnt,
                          unsigned short* __restrict__ w1bf, unsigned short* __restrict__ w2bf) {
    int k  = blockIdx.x * 256 + threadIdx.x;
    int si = blockIdx.y;
    int s_ = si / 3, i_ = si % 3;
    const int* ind = (i_ == 0 ? ind0 : (i_ == 1 ? ind1 : ind2)) + (size_t)s_ * NIND * 2;
    int c0 = ind[2 * k];
    inv[(size_t)si * NIND + c0] = k;
    if (si == 0) mergecnt[k] = 0;
    if (blockIdx.x == 0 && blockIdx.y == 0) {
        int t = threadIdx.x;
        for (int i = t; i < 64 * 32; i += 256) {
            int j = i >> 5, kk = i & 31;
            w1bf[i] = (kk < 24) ? (unsigned short)(cvtpk(w1[j * 24 + kk], 0.f) & 0xffff) : 0;
        }
        for (int i = t; i < 16 * 64; i += 256) {
            int f = i >> 6, kg = i & 63;
            int hi = kg >> 5, q = (kg >> 3) & 3, e = kg & 7;
            int j = (hi << 5) + ((e >> 2) << 4) + (q << 2) + (e & 3);   // tau
            w2bf[i] = (f < 8) ? (unsigned short)(cvtpk(w2[f * 64 + j], 0.f) & 0xffff) : 0;
        }
    }
}

// ---------------- bucket-invert the scatter into ONE merged list per column --
// mergelist[c][slot] = s*MDIM + m  (the d-tile index contributing to column c)
__global__ void build_buckets(const int* __restrict__ ind0, const int* __restrict__ ind1,
                              const int* __restrict__ ind2, const int* __restrict__ mix,
                              int* __restrict__ mergecnt, int* __restrict__ mergelist) {
    int m  = blockIdx.x * 256 + threadIdx.x;
    int si = blockIdx.y;
    int s_ = si / 3, i_ = si % 3;
    const int* ind = (i_ == 0 ? ind0 : (i_ == 1 ? ind1 : ind2)) + (size_t)s_ * NIND * 2;
    int mi = mix[(size_t)si * MDIM + m];
    int c  = ind[2 * mi + 1];
    int slot = atomicAdd(&mergecnt[c], 1);
    if (slot < MAXL) mergelist[(size_t)c * MAXL + slot] = s_ * MDIM + m;
}

// ---------------- MFMA MLP -> dense d[s*M+m][r][f] bf16 (clamped at 0) -----
// One wave per (s, half-of-r, group of MPW m). Fully in-register; w2 columns
// pre-permuted by tau so layer-1's packed relu output IS the layer-2 B frag.
// Loop-invariant fragments (A1/A2/bbv/b2f) are PINNED via opaque empty asm so
// the allocator cannot rematerialize them per-iteration (R10: VGPR_Count=44
// meant ~4x VALU bloat from re-loading weights every iteration).
__global__ __launch_bounds__(256, 2)
void mlp_store(const unsigned short* __restrict__ inT2,
               const unsigned short* __restrict__ w1bf,
               const unsigned short* __restrict__ w2bf,
               const float* __restrict__ b1, const float* __restrict__ b2,
               const int* __restrict__ ind0, const int* __restrict__ ind1,
               const int* __restrict__ ind2, const int* __restrict__ mix,
               const int* __restrict__ inv,
               unsigned short* __restrict__ dbuf) {
    int t    = threadIdx.x;
    int wave = t >> 6, lane = t & 63;
    int lo = lane & 15, q = lane >> 4;

    int wid  = blockIdx.x * 4 + wave;    // 0..6143
    int mgrp = wid & 1023;
    int half = (wid >> 10) & 1;
    int s_   = wid >> 11;
    int m0   = mgrp * MPW;

    short8 A1[4], A2[2];
#pragma unroll
    for (int tt = 0; tt < 4; tt++)
        A1[tt] = *(const short8*)(w1bf + ((16 * tt + lo) << 5) + (q << 3));
#pragma unroll
    for (int kk = 0; kk < 2; kk++)
        A2[kk] = *(const short8*)(w2bf + (lo << 6) + (kk << 5) + (q << 3));

    // biases as MFMA C-operand fragments
    f32x4 bbv[4];
#pragma unroll
    for (int tt = 0; tt < 4; tt++)
#pragma unroll
        for (int rg = 0; rg < 4; rg++)
            bbv[tt][rg] = b1[16 * tt + 4 * q + rg];
    f32x4 b2f;
#pragma unroll
    for (int rg = 0; rg < 4; rg++) {
        int f = 4 * q + rg;
        b2f[rg] = (f < 8) ? b2[f] : 0.f;
    }

    // pin invariants: opaque asm kills rematerialization -> held in VGPRs
#pragma unroll
    for (int tt = 0; tt < 4; tt++) asm volatile("" : "+v"(A1[tt]));
    asm volatile("" : "+v"(A2[0]), "+v"(A2[1]));
#pragma unroll
    for (int tt = 0; tt < 4; tt++) asm volatile("" : "+v"(bbv[tt]));
    asm volatile("" : "+v"(b2f));

    // batched index chase: 3 rounds of MPW independent loads
    int gq[MPW] = {0, 0, 0, 0};
    if (q < 3) {
        int si = s_ * 3 + q;
        const int* indq = (q == 0 ? ind0 : (q == 1 ? ind1 : ind2)) + (size_t)s_ * NIND * 2;
        int mi[MPW], kk[MPW];
#pragma unroll
        for (int u = 0; u < MPW; u++) mi[u] = mix[(size_t)si * MDIM + m0 + u];
#pragma unroll
        for (int u = 0; u < MPW; u++) kk[u] = inv[(size_t)si * NIND + mi[u]];
#pragma unroll
        for (int u = 0; u < MPW; u++) gq[u] = indq[2 * kk[u] + 1];
    }
    const unsigned short* srcs[MPW];
#pragma unroll
    for (int u = 0; u < MPW; u++)
        srcs[u] = inT2 + ((size_t)gq[u] * RDIM + half * 128 + lo) * 8;

    unsigned short* dst = dbuf + (size_t)(s_ * MDIM + m0) * 2048 + half * 1024 + lo * 8 + q * 4;

    union U { unsigned int u[4]; short8 s; };
    const short8 zero8 = {0, 0, 0, 0, 0, 0, 0, 0};

    short8 Bcur = zero8;
    if (q < 3) Bcur = *(const short8*)srcs[0];
#pragma unroll
    for (int it = 0; it < MPW * 8; it++) {
        const int u = it >> 3, j = it & 7;
        short8 Bnext = Bcur;
        if (it < MPW * 8 - 1 && q < 3)
            Bnext = *(const short8*)(srcs[(it + 1) >> 3] + ((it + 1) & 7) * 128);

        f32x4 a0 = __builtin_amdgcn_mfma_f32_16x16x32_bf16(A1[0], Bcur, bbv[0], 0, 0, 0);
        f32x4 a1 = __builtin_amdgcn_mfma_f32_16x16x32_bf16(A1[1], Bcur, bbv[1], 0, 0, 0);
        f32x4 a2 = __builtin_amdgcn_mfma_f32_16x16x32_bf16(A1[2], Bcur, bbv[2], 0, 0, 0);
        f32x4 a3 = __builtin_amdgcn_mfma_f32_16x16x32_bf16(A1[3], Bcur, bbv[3], 0, 0, 0);

        // relu (fmaxf: also NaN-squashing) + bf16 pack: result IS the layer-2
        // B fragment (tau-permuted w2)
        U ba, bb;
        ba.u[0] = cvtpk(fmaxf(a0[0], 0.f), fmaxf(a0[1], 0.f));
        ba.u[1] = cvtpk(fmaxf(a0[2], 0.f), fmaxf(a0[3], 0.f));
        ba.u[2] = cvtpk(fmaxf(a1[0], 0.f), fmaxf(a1[1], 0.f));
        ba.u[3] = cvtpk(fmaxf(a1[2], 0.f), fmaxf(a1[3], 0.f));
        bb.u[0] = cvtpk(fmaxf(a2[0], 0.f), fmaxf(a2[1], 0.f));
        bb.u[1] = cvtpk(fmaxf(a2[2], 0.f), fmaxf(a2[3], 0.f));
        bb.u[2] = cvtpk(fmaxf(a3[0], 0.f), fmaxf(a3[1], 0.f));
        bb.u[3] = cvtpk(fmaxf(a3[2], 0.f), fmaxf(a3[3], 0.f));

        f32x4 o = __builtin_amdgcn_mfma_f32_16x16x32_bf16(A2[0], ba.s, b2f, 0, 0, 0);
        o = __builtin_amdgcn_mfma_f32_16x16x32_bf16(A2[1], bb.s, o, 0, 0, 0);

        if (q < 2) {   // store d (clamped at 0; negatives never beat zeros baseline)
            uint2 ov;
            ov.x = cvtpk(fmaxf(o[0], 0.f), fmaxf(o[1], 0.f));
            ov.y = cvtpk(fmaxf(o[2], 0.f), fmaxf(o[3], 0.f));
            *(uint2*)(dst + (size_t)u * 2048 + j * 128) = ov;
        }
        Bcur = Bnext;
    }
}

// ---------------- gather-max per dest column -> d_out [f][r][c] directly ------
// grid (CDIM/GC, 4); 1024-thread block = 16 waves; wave w owns column c0+w,
// lane = row within the 64-row slab. 2-wide dual-accumulator unroll (max is
// idempotent: odd lists padded by duplicating the last entry) keeps 4 x 1KB
// wave-loads in flight. NaN-squashing unpack at the end.
__global__ __launch_bounds__(1024)
void gather_max_t(const unsigned short* __restrict__ dbuf, const int* __restrict__ mergecnt,
                  const int* __restrict__ mergelist, float* __restrict__ out) {
    __shared__ unsigned int ldsP[4][64][20];   // [f/2][rloc][c] packed bf16 pairs
    __shared__ int mlist[GC][MAXL + 2];
    int t = threadIdx.x;
    int w = t >> 6, lane = t & 63;
    int c0 = blockIdx.x * GC;
    int c  = c0 + w;

    int n = mergecnt[c];
    n = n < 0 ? 0 : (n > MAXL ? MAXL : n);        // uniform across the wave
    if (lane < n) {
        int idx = mergelist[(size_t)c * MAXL + lane];
        idx = idx < 0 ? 0 : (idx >= NSETS * MDIM ? NSETS * MDIM - 1 : idx);
        mlist[w][lane] = idx;
    }
    if (lane == 0 && (n & 1)) {                   // pad odd list: dup last (max-idempotent)
        int idx = mergelist[(size_t)c * MAXL + (n - 1)];
        idx = idx < 0 ? 0 : (idx >= NSETS * MDIM ? NSETS * MDIM - 1 : idx);
        mlist[w][n] = idx;
    }
    __syncthreads();
    int n2 = n + (n & 1);

    int r = blockIdx.y * 64 + lane;
    uint4 acc = make_uint4(0u, 0u, 0u, 0u);
    if (n2 > 0) {
        uint4 a0 = make_uint4(0u, 0u, 0u, 0u);
        uint4 a1 = make_uint4(0u, 0u, 0u, 0u);
        uint4 pa = *(const uint4*)(dbuf + ((size_t)mlist[w][0] * RDIM + r) * 8);
        uint4 pb = *(const uint4*)(dbuf + ((size_t)mlist[w][1] * RDIM + r) * 8);
        for (int e = 2; e < n2; e += 2) {
            uint4 qa = *(const uint4*)(dbuf + ((size_t)mlist[w][e] * RDIM + r) * 8);
            uint4 qb = *(const uint4*)(dbuf + ((size_t)mlist[w][e + 1] * RDIM + r) * 8);
            a0.x = pkmaxu(a0.x, pa.x); a0.y = pkmaxu(a0.y, pa.y);
            a0.z = pkmaxu(a0.z, pa.z); a0.w = pkmaxu(a0.w, pa.w);
            a1.x = pkmaxu(a1.x, pb.x); a1.y = pkmaxu(a1.y, pb.y);
            a1.z = pkmaxu(a1.z, pb.z); a1.w = pkmaxu(a1.w, pb.w);
            pa = qa; pb = qb;
        }
        a0.x = pkmaxu(a0.x, pa.x); a0.y = pkmaxu(a0.y, pa.y);
        a0.z = pkmaxu(a0.z, pa.z); a0.w = pkmaxu(a0.w, pa.w);
        a1.x = pkmaxu(a1.x, pb.x); a1.y = pkmaxu(a1.y, pb.y);
        a1.z = pkmaxu(a1.z, pb.z); a1.w = pkmaxu(a1.w, pb.w);
        acc.x = pkmaxu(a0.x, a1.x); acc.y = pkmaxu(a0.y, a1.y);
        acc.z = pkmaxu(a0.z, a1.z); acc.w = pkmaxu(a0.w, a1.w);
    }

    ldsP[0][lane][w] = acc.x;
    ldsP[1][lane][w] = acc.y;
    ldsP[2][lane][w] = acc.z;
    ldsP[3][lane][w] = acc.w;
    __syncthreads();

    // one (f-pair, row, c-quad) per thread: 1024 = 4 * 64 * 4.
    // fmaxf(x, 0) is identity on all legit values (>=0) and squashes NaN/neg.
    int f2 = t >> 8, rl = (t >> 2) & 63, cq = t & 3;
    uint4 v = *(const uint4*)&ldsP[f2][rl][cq * 4];
    float4 lo, hi;
    lo.x = fmaxf(__uint_as_float(v.x << 16), 0.f);
    hi.x = fmaxf(__uint_as_float(v.x & 0xffff0000u), 0.f);
    lo.y = fmaxf(__uint_as_float(v.y << 16), 0.f);
    hi.y = fmaxf(__uint_as_float(v.y & 0xffff0000u), 0.f);
    lo.z = fmaxf(__uint_as_float(v.z << 16), 0.f);
    hi.z = fmaxf(__uint_as_float(v.z & 0xffff0000u), 0.f);
    lo.w = fmaxf(__uint_as_float(v.w << 16), 0.f);
    hi.w = fmaxf(__uint_as_float(v.w & 0xffff0000u), 0.f);
    size_t rowoff = (size_t)blockIdx.y * 64 + rl;
    *(float4*)&out[((size_t)(2 * f2) * RDIM + rowoff) * CDIM + c0 + cq * 4] = lo;
    *(float4*)&out[((size_t)(2 * f2 + 1) * RDIM + rowoff) * CDIM + c0 + cq * 4] = hi;
}

extern "C" void kernel_launch(void* const* d_in, const int* in_sizes, int n_in,
                              void* d_out, int out_size, void* d_ws, size_t ws_size,
                              hipStream_t stream) {
    const float* input = (const float*)d_in[0];
    const float* w1    = (const float*)d_in[1];
    const float* b1    = (const float*)d_in[2];
    const float* w2    = (const float*)d_in[3];
    const float* b2    = (const float*)d_in[4];
    const int*   ind0  = (const int*)d_in[5];
    const int*   ind1  = (const int*)d_in[6];
    const int*   ind2  = (const int*)d_in[7];
    const int*   mix   = (const int*)d_in[8];

    const size_t MiB = 1ull << 20;
    char* ws = (char*)d_ws;
    unsigned short* inT2 = (unsigned short*)ws;                    // 16 MiB
    unsigned short* dbuf = (unsigned short*)(ws + 16 * MiB);       // 48 MiB
    char* tail = ws + 64 * MiB;
    int* inv       = (int*)tail;                                   // 144 KiB
    int* mergecnt  = (int*)(tail + 147456);                        // 16 KiB
    int* mergelist = (int*)(tail + 147456 + 16384);                // 1 MiB
    unsigned short* w1bf = (unsigned short*)(tail + 147456 + 16384 + (size_t)CDIM * MAXL * 4);
    unsigned short* w2bf = w1bf + 64 * 32;

    prep_in<<<dim3(CDIM / 32, RDIM / 32), 256, 0, stream>>>(input, inT2);
    build_inv<<<dim3(NIND / 256, 9), 256, 0, stream>>>(ind0, ind1, ind2, w1, w2,
                                                       inv, mergecnt, w1bf, w2bf);
    build_buckets<<<dim3(MDIM / 256, 9), 256, 0, stream>>>(ind0, ind1, ind2, mix,
                                                           mergecnt, mergelist);
    mlp_store<<<NSETS * 2 * (MDIM / MPW) / 4, 256, 0, stream>>>(inT2, w1bf, w2bf, b1, b2,
                                                                ind0, ind1, ind2, mix, inv, dbuf);
    gather_max_t<<<dim3(CDIM / GC, 4), 1024, 0, stream>>>(dbuf, mergecnt, mergelist,
                                                          (float*)d_out);
}